// Round 3
// baseline (113.976 us; speedup 1.0000x reference)
//
#include <hip/hip_runtime.h>
#include <math.h>

#define Bv 4
#define Nv 512
#define Dv 128
#define BND (Bv*Nv*Dv)      // 262144
#define NN  (Nv*Nv)         // 262144
#define EPSv 1e-9f

typedef float f2 __attribute__((ext_vector_type(2)));

// -------------------------------------------------------------------------
// k_prep: (a) gumbel-softmax row `bi` -> 4 batch copies of A (computed ONCE,
//         not once per batch); (b) proj = ES@Wp+bp for 4 rows; (c) s'/t.
//         Grid 512 -> 2 blocks/CU -> 2 waves/SIMD for latency hiding.
// -------------------------------------------------------------------------
__global__ __launch_bounds__(256) void k_prep(
    const float* __restrict__ ES, const float* __restrict__ Wp,
    const float* __restrict__ bp, const float* __restrict__ W1,
    const float* __restrict__ b1, const float* __restrict__ EL,
    const float* __restrict__ UN,
    float* __restrict__ s_out, float* __restrict__ t_out,
    float* __restrict__ A_out)
{
    __shared__ float es[4][Dv];
    __shared__ float pr[4][Dv];
    __shared__ float sred[4];
    const int bi = blockIdx.x;        // 0..511
    const int t  = threadIdx.x;

    // ---- phase A: softmax((EL+gumbel)/TAU) for row bi, broadcast to 4 b's
    {
        const int row = bi;
        const float u0 = UN[row*Nv + t];
        const float u1 = UN[row*Nv + t + 256];
        const float g0 = -logf(-logf(u0 + EPSv) + EPSv);
        const float g1 = -logf(-logf(u1 + EPSv) + EPSv);
        const float z0 = (EL[row*Nv + t]       + g0) * 2.0f;   // 1/TAU = 2
        const float z1 = (EL[row*Nv + t + 256] + g1) * 2.0f;

        float m = fmaxf(z0, z1);
        #pragma unroll
        for (int off = 32; off >= 1; off >>= 1)
            m = fmaxf(m, __shfl_xor(m, off, 64));
        if ((t & 63) == 0) sred[t >> 6] = m;
        __syncthreads();
        m = fmaxf(fmaxf(sred[0], sred[1]), fmaxf(sred[2], sred[3]));

        const float e0 = expf(z0 - m);
        const float e1 = expf(z1 - m);
        float ssum = e0 + e1;
        #pragma unroll
        for (int off = 32; off >= 1; off >>= 1)
            ssum += __shfl_xor(ssum, off, 64);
        __syncthreads();
        if ((t & 63) == 0) sred[t >> 6] = ssum;
        __syncthreads();
        const float inv = 1.0f / (sred[0] + sred[1] + sred[2] + sred[3]);
        const float a0 = e0 * inv;
        const float a1 = e1 * inv;
        #pragma unroll
        for (int bb = 0; bb < Bv; ++bb) {
            A_out[bb*NN + row*Nv + t]       = a0;
            A_out[bb*NN + row*Nv + t + 256] = a1;
        }
    }

    // ---- phase B: proj for rows bi*4 .. bi*4+3
    const int row0 = bi * 4;
    const int c  = t & 127;
    const int rg = t >> 7;            // 0..1 -> rows rg*2, rg*2+1

    for (int idx = t; idx < 4*Dv; idx += 256)
        es[idx >> 7][idx & 127] = ES[(row0 + (idx >> 7))*Dv + (idx & 127)];
    __syncthreads();

    {
        float acc[2];
        const float bpc = bp[c];
        acc[0] = bpc; acc[1] = bpc;
        #pragma unroll 8
        for (int k = 0; k < Dv; ++k) {
            const float w = Wp[k*Dv + c];
            acc[0] = fmaf(es[rg*2][k],   w, acc[0]);
            acc[1] = fmaf(es[rg*2+1][k], w, acc[1]);
        }
        pr[rg*2][c]   = acc[0];
        pr[rg*2+1][c] = acc[1];
    }
    __syncthreads();

    // ---- phase C: s' = proj@W1_src + b1, t = proj@W1_tgt
    float sacc0 = b1[c], sacc1 = sacc0, tacc0 = 0.0f, tacc1 = 0.0f;
    #pragma unroll 8
    for (int k = 0; k < Dv; ++k) {
        const float ws_ = W1[k*Dv + c];
        const float wt_ = W1[(Dv + k)*Dv + c];
        const float p0 = pr[rg*2][k];
        const float p1 = pr[rg*2+1][k];
        sacc0 = fmaf(p0, ws_, sacc0);
        sacc1 = fmaf(p1, ws_, sacc1);
        tacc0 = fmaf(p0, wt_, tacc0);
        tacc1 = fmaf(p1, wt_, tacc1);
    }
    const int ra = (row0 + rg*2)*Dv + c;
    s_out[ra]      = sacc0;
    s_out[ra + Dv] = sacc1;
    t_out[ra]      = tacc0;
    t_out[ra + Dv] = tacc1;
}

// -------------------------------------------------------------------------
// k_main: block = (4 i-rows, batch b), 256 threads, thread = (i-pair, 1 d).
//   hsum[i,d] = sum_j A[i,j]*relu(s'[b,j,d]+t[b,i,d]); s' in 128x128 LDS
//   tiles (64KB, 2 blocks/CU). A read from global b=0 copy with
//   WAVE-UNIFORM addresses -> scalar s_load pipe (no LDS/VALU cost).
//   i-pair packed as float2 -> v_pk_add/v_pk_fma.
//   Epilogue: out = ES + hsum@W2 + b2 (sum_j A == 1 exactly).
// -------------------------------------------------------------------------
__global__ __launch_bounds__(256) void k_main(
    const float* __restrict__ s_buf, const float* __restrict__ t_buf,
    const float* __restrict__ A0,    const float* __restrict__ ES,
    const float* __restrict__ W2,    const float* __restrict__ b2,
    float* __restrict__ out)
{
    const int JT = 128;
    __shared__ float sj[JT][Dv];      // 64 KB; reused as hs[4][128] in epilogue
    const int i0 = blockIdx.x * 4;
    const int b  = blockIdx.y;
    const int t  = threadIdx.x;
    const int d  = t & 127;
    const int p  = __builtin_amdgcn_readfirstlane(t >> 7);   // uniform pair id
    const int ia = i0 + 2*p;

    f2 tv;
    tv.x = t_buf[(b*Nv + ia)*Dv + d];
    tv.y = t_buf[(b*Nv + ia + 1)*Dv + d];
    const float* __restrict__ Ar0 = A0 + ia*Nv;        // uniform base
    const float* __restrict__ Ar1 = A0 + (ia + 1)*Nv;  // uniform base

    f2 acc; acc.x = 0.0f; acc.y = 0.0f;
    for (int jt = 0; jt < Nv; jt += JT) {
        __syncthreads();
        const float4* __restrict__ src = (const float4*)(s_buf + (b*Nv + jt)*Dv);
        float4* dst = (float4*)(&sj[0][0]);
        #pragma unroll
        for (int u = 0; u < 16; ++u)
            dst[t + u*256] = src[t + u*256];
        __syncthreads();
        #pragma unroll 4
        for (int j = 0; j < JT; ++j) {
            const float a0 = Ar0[jt + j];    // uniform addr -> s_load
            const float a1 = Ar1[jt + j];    // uniform addr -> s_load
            const float sv = sj[j][d];
            f2 z; z.x = sv + tv.x; z.y = sv + tv.y;
            f2 r; r.x = fmaxf(z.x, 0.0f); r.y = fmaxf(z.y, 0.0f);
            acc.x = fmaf(a0, r.x, acc.x);
            acc.y = fmaf(a1, r.y, acc.y);
        }
    }

    // ---- epilogue: out = ES + hsum@W2 + b2
    __syncthreads();
    sj[2*p][d]     = acc.x;
    sj[2*p + 1][d] = acc.y;
    __syncthreads();

    const int c  = t & 127;
    const int rg = t >> 7;            // rows rg*2, rg*2+1
    float o0 = b2[c], o1 = o0;
    #pragma unroll 8
    for (int k = 0; k < Dv; ++k) {
        const float w2 = W2[k*Dv + c];
        o0 = fmaf(sj[rg*2][k],   w2, o0);
        o1 = fmaf(sj[rg*2+1][k], w2, o1);
    }
    const int ro0 = (b*Nv + i0 + rg*2)*Dv + c;
    out[ro0]      = ES[ro0]      + o0;
    out[ro0 + Dv] = ES[ro0 + Dv] + o1;
}

extern "C" void kernel_launch(void* const* d_in, const int* in_sizes, int n_in,
                              void* d_out, int out_size, void* d_ws, size_t ws_size,
                              hipStream_t stream) {
    (void)in_sizes; (void)n_in; (void)out_size; (void)ws_size;
    const float* ES = (const float*)d_in[0];
    const float* Wp = (const float*)d_in[1];
    const float* bp = (const float*)d_in[2];
    const float* EL = (const float*)d_in[3];
    const float* W1 = (const float*)d_in[4];
    const float* b1 = (const float*)d_in[5];
    const float* W2 = (const float*)d_in[6];
    const float* b2 = (const float*)d_in[7];
    const float* UN = (const float*)d_in[8];

    float* out   = (float*)d_out;
    float* A_out = out + BND;            // A broadcast region: B*N*N floats

    float* s_buf = (float*)d_ws;         // s' = proj@W1_src + b1  (B*N*D)
    float* t_buf = s_buf + BND;          // t  = proj@W1_tgt       (B*N*D)

    k_prep<<<512, 256, 0, stream>>>(ES, Wp, bp, W1, b1, EL, UN,
                                    s_buf, t_buf, A_out);
    k_main<<<dim3(Nv/4, Bv), 256, 0, stream>>>(s_buf, t_buf, A_out, ES, W2, b2,
                                               out);
}

// Round 4
// 110.207 us; speedup vs baseline: 1.0342x; 1.0342x over previous
//
#include <hip/hip_runtime.h>
#include <math.h>

#define Bv 4
#define Nv 512
#define Dv 128
#define BND (Bv*Nv*Dv)      // 262144
#define NN  (Nv*Nv)         // 262144
#define EPSv 1e-9f

typedef float f4 __attribute__((ext_vector_type(4)));

__device__ __forceinline__ f4 relu4(f4 z) {
#if __has_builtin(__builtin_elementwise_max)
    return __builtin_elementwise_max(z, (f4)0.0f);
#else
    z.x = fmaxf(z.x, 0.0f); z.y = fmaxf(z.y, 0.0f);
    z.z = fmaxf(z.z, 0.0f); z.w = fmaxf(z.w, 0.0f);
    return z;
#endif
}

// -------------------------------------------------------------------------
// k_prep (unchanged from R3, known-good): (a) gumbel-softmax row bi -> 4
// batch copies of A; (b) proj = ES@Wp+bp for 4 rows; (c) s'/t.
// Grid 512 -> 2 blocks/CU.
// -------------------------------------------------------------------------
__global__ __launch_bounds__(256) void k_prep(
    const float* __restrict__ ES, const float* __restrict__ Wp,
    const float* __restrict__ bp, const float* __restrict__ W1,
    const float* __restrict__ b1, const float* __restrict__ EL,
    const float* __restrict__ UN,
    float* __restrict__ s_out, float* __restrict__ t_out,
    float* __restrict__ A_out)
{
    __shared__ float es[4][Dv];
    __shared__ float pr[4][Dv];
    __shared__ float sred[4];
    const int bi = blockIdx.x;        // 0..511
    const int t  = threadIdx.x;

    // ---- phase A: softmax((EL+gumbel)/TAU) for row bi, broadcast to 4 b's
    {
        const int row = bi;
        const float u0 = UN[row*Nv + t];
        const float u1 = UN[row*Nv + t + 256];
        const float g0 = -logf(-logf(u0 + EPSv) + EPSv);
        const float g1 = -logf(-logf(u1 + EPSv) + EPSv);
        const float z0 = (EL[row*Nv + t]       + g0) * 2.0f;   // 1/TAU = 2
        const float z1 = (EL[row*Nv + t + 256] + g1) * 2.0f;

        float m = fmaxf(z0, z1);
        #pragma unroll
        for (int off = 32; off >= 1; off >>= 1)
            m = fmaxf(m, __shfl_xor(m, off, 64));
        if ((t & 63) == 0) sred[t >> 6] = m;
        __syncthreads();
        m = fmaxf(fmaxf(sred[0], sred[1]), fmaxf(sred[2], sred[3]));

        const float e0 = expf(z0 - m);
        const float e1 = expf(z1 - m);
        float ssum = e0 + e1;
        #pragma unroll
        for (int off = 32; off >= 1; off >>= 1)
            ssum += __shfl_xor(ssum, off, 64);
        __syncthreads();
        if ((t & 63) == 0) sred[t >> 6] = ssum;
        __syncthreads();
        const float inv = 1.0f / (sred[0] + sred[1] + sred[2] + sred[3]);
        const float a0 = e0 * inv;
        const float a1 = e1 * inv;
        #pragma unroll
        for (int bb = 0; bb < Bv; ++bb) {
            A_out[bb*NN + row*Nv + t]       = a0;
            A_out[bb*NN + row*Nv + t + 256] = a1;
        }
    }

    // ---- phase B: proj for rows bi*4 .. bi*4+3
    const int row0 = bi * 4;
    const int c  = t & 127;
    const int rg = t >> 7;            // 0..1 -> rows rg*2, rg*2+1

    for (int idx = t; idx < 4*Dv; idx += 256)
        es[idx >> 7][idx & 127] = ES[(row0 + (idx >> 7))*Dv + (idx & 127)];
    __syncthreads();

    {
        float acc[2];
        const float bpc = bp[c];
        acc[0] = bpc; acc[1] = bpc;
        #pragma unroll 8
        for (int k = 0; k < Dv; ++k) {
            const float w = Wp[k*Dv + c];
            acc[0] = fmaf(es[rg*2][k],   w, acc[0]);
            acc[1] = fmaf(es[rg*2+1][k], w, acc[1]);
        }
        pr[rg*2][c]   = acc[0];
        pr[rg*2+1][c] = acc[1];
    }
    __syncthreads();

    // ---- phase C: s' = proj@W1_src + b1, t = proj@W1_tgt
    float sacc0 = b1[c], sacc1 = sacc0, tacc0 = 0.0f, tacc1 = 0.0f;
    #pragma unroll 8
    for (int k = 0; k < Dv; ++k) {
        const float ws_ = W1[k*Dv + c];
        const float wt_ = W1[(Dv + k)*Dv + c];
        const float p0 = pr[rg*2][k];
        const float p1 = pr[rg*2+1][k];
        sacc0 = fmaf(p0, ws_, sacc0);
        sacc1 = fmaf(p1, ws_, sacc1);
        tacc0 = fmaf(p0, wt_, tacc0);
        tacc1 = fmaf(p1, wt_, tacc1);
    }
    const int ra = (row0 + rg*2)*Dv + c;
    s_out[ra]      = sacc0;
    s_out[ra + Dv] = sacc1;
    t_out[ra]      = tacc0;
    t_out[ra + Dv] = tacc1;
}

// -------------------------------------------------------------------------
// k_main R4: block = (8 i-rows, b), grid (64,4)=256 blocks (1/CU).
// Thread = (d-quad dq: 4 consecutive d's, j-group jg: 64 contiguous js).
// - sv read directly from global as b128 (L2-resident; amortized over 8 i's)
// - A in LDS (16KB), read b128 per 4 j per row (amortized over 4 d x 4 j)
// - 32 f32 accumulators/thread; j-loop is VALU-bound by design:
//   per wave per j: VALU 96 cyc (48 if pk) vs LDS 24 vs VMEM ~8.
// - jg-partials reduced via LDS; epilogue GEMM 2 rows x 2 cols/thread with
//   b128 hsum reads; out = ES + hsum@W2 + b2 (sum_j A == 1 exactly).
// -------------------------------------------------------------------------
__global__ __launch_bounds__(256) void k_main(
    const float* __restrict__ s_buf, const float* __restrict__ t_buf,
    const float* __restrict__ A0,    const float* __restrict__ ES,
    const float* __restrict__ W2,    const float* __restrict__ b2,
    float* __restrict__ out)
{
    __shared__ float A_lds[8][Nv];    // 16 KB
    __shared__ f4    part[8][8][32];  // 32 KB [jg][i][dq]
    __shared__ float hsum[8][Dv];     // 4 KB
    const int i0 = blockIdx.x * 8;
    const int b  = blockIdx.y;
    const int t  = threadIdx.x;
    const int dq = t & 31;            // d = dq*4 .. dq*4+3
    const int jg = t >> 5;            // 0..7 -> j in [jg*64, jg*64+64)

    // stage A rows i0..i0+7 (b-independent copy 0), coalesced f4
    {
        const f4* __restrict__ src = (const f4*)(A0 + i0*Nv);
        f4* dst = (f4*)(&A_lds[0][0]);
        #pragma unroll
        for (int u = 0; u < 4; ++u)
            dst[t + u*256] = src[t + u*256];
    }

    f4 tv[8];
    #pragma unroll
    for (int r = 0; r < 8; ++r)
        tv[r] = *(const f4*)(t_buf + (b*Nv + i0 + r)*Dv + dq*4);

    f4 acc[8];
    #pragma unroll
    for (int r = 0; r < 8; ++r) acc[r] = (f4)0.0f;

    __syncthreads();                  // A_lds ready

    const float* __restrict__ sb = s_buf + (size_t)b*Nv*Dv + dq*4;
    const int j0 = jg*64;
    for (int j4 = j0; j4 < j0 + 64; j4 += 4) {
        f4 a[8];
        #pragma unroll
        for (int r = 0; r < 8; ++r)
            a[r] = *(const f4*)(&A_lds[r][j4]);        // b128, 4 js of row r
        #pragma unroll
        for (int u = 0; u < 4; ++u) {
            const f4 sv = *(const f4*)(sb + (j4 + u)*Dv);  // global b128 (L2)
            #pragma unroll
            for (int r = 0; r < 8; ++r) {
                f4 z = relu4(sv + tv[r]);
                acc[r] += a[r][u] * z;                 // fma (ffp-contract)
            }
        }
    }

    // jg-partials -> LDS, reduce 8-way
    #pragma unroll
    for (int r = 0; r < 8; ++r) part[jg][r][dq] = acc[r];
    __syncthreads();
    {
        const int ri = t >> 5;        // 0..7
        f4 s = part[0][ri][dq];
        #pragma unroll
        for (int g = 1; g < 8; ++g) s += part[g][ri][dq];
        *(f4*)(&hsum[ri][dq*4]) = s;
    }
    __syncthreads();

    // epilogue: out = ES + hsum@W2 + b2; thread = (2 cols, 2 rows)
    const int cg = t & 63;            // cols c0=2cg, c0+1
    const int rg = t >> 6;            // rows r0=2rg, r0+1
    const int c0 = 2*cg;
    const int r0 = 2*rg;
    float o00 = b2[c0], o01 = b2[c0+1];
    float o10 = o00,    o11 = o01;
    for (int k4 = 0; k4 < Dv; k4 += 4) {
        const f4 h0 = *(const f4*)(&hsum[r0][k4]);     // b128
        const f4 h1 = *(const f4*)(&hsum[r0+1][k4]);   // b128
        #pragma unroll
        for (int u = 0; u < 4; ++u) {
            const float2 w = *(const float2*)(W2 + (k4 + u)*Dv + c0);
            o00 = fmaf(h0[u], w.x, o00);
            o01 = fmaf(h0[u], w.y, o01);
            o10 = fmaf(h1[u], w.x, o10);
            o11 = fmaf(h1[u], w.y, o11);
        }
    }
    const int ro0 = (b*Nv + i0 + r0)*Dv + c0;
    const int ro1 = ro0 + Dv;
    const float2 e0 = *(const float2*)(ES + ro0);
    const float2 e1 = *(const float2*)(ES + ro1);
    float2 v0, v1;
    v0.x = e0.x + o00; v0.y = e0.y + o01;
    v1.x = e1.x + o10; v1.y = e1.y + o11;
    *(float2*)(out + ro0) = v0;
    *(float2*)(out + ro1) = v1;
}

extern "C" void kernel_launch(void* const* d_in, const int* in_sizes, int n_in,
                              void* d_out, int out_size, void* d_ws, size_t ws_size,
                              hipStream_t stream) {
    (void)in_sizes; (void)n_in; (void)out_size; (void)ws_size;
    const float* ES = (const float*)d_in[0];
    const float* Wp = (const float*)d_in[1];
    const float* bp = (const float*)d_in[2];
    const float* EL = (const float*)d_in[3];
    const float* W1 = (const float*)d_in[4];
    const float* b1 = (const float*)d_in[5];
    const float* W2 = (const float*)d_in[6];
    const float* b2 = (const float*)d_in[7];
    const float* UN = (const float*)d_in[8];

    float* out   = (float*)d_out;
    float* A_out = out + BND;            // A broadcast region: B*N*N floats

    float* s_buf = (float*)d_ws;         // s' = proj@W1_src + b1  (B*N*D)
    float* t_buf = s_buf + BND;          // t  = proj@W1_tgt       (B*N*D)

    k_prep<<<512, 256, 0, stream>>>(ES, Wp, bp, W1, b1, EL, UN,
                                    s_buf, t_buf, A_out);
    k_main<<<dim3(Nv/8, Bv), 256, 0, stream>>>(s_buf, t_buf, A_out, ES, W2, b2,
                                               out);
}